// Round 14
// baseline (140.361 us; speedup 1.0000x reference)
//
#include <hip/hip_runtime.h>
#include <cmath>

typedef __bf16 bf16x8 __attribute__((ext_vector_type(8)));
typedef float f32x4 __attribute__((ext_vector_type(4)));
typedef unsigned int u32x4 __attribute__((ext_vector_type(4)));

#define SEQ 2048
#define EMBED 768
#define NHEAD 12
#define HDIM 64
#define NTOK 4096   // BS*SEQ
#define NBH 24      // BS*NHEAD
#define NSPLIT 4
#define TILES_PER_SPLIT (SEQ / 64 / NSPLIT)  // 8
// base-2 logits: fold log2(e)/sqrt(768) into the q projection
#define SCALE_LOG2 (1.4426950408889634f * 0.036084391824351615f)

// ---------- helpers ----------
__device__ __forceinline__ void gload_lds16(const __bf16* g, __bf16* l) {
  __builtin_amdgcn_global_load_lds(
      (const __attribute__((address_space(1))) void*)g,
      (__attribute__((address_space(3))) void*)l, 16, 0, 0);
}

__device__ __forceinline__ unsigned pack2(float a, float b) {
  unsigned short lo = __builtin_bit_cast(unsigned short, (__bf16)a);
  unsigned short hi = __builtin_bit_cast(unsigned short, (__bf16)b);
  return (unsigned)lo | ((unsigned)hi << 16);
}

// one barrier per pipeline phase (GEMM only)
__device__ __forceinline__ void phase_barrier() {
  asm volatile("s_waitcnt vmcnt(0)" ::: "memory");
  __builtin_amdgcn_s_barrier();
  __builtin_amdgcn_sched_barrier(0);
}

// ---------- fp32 -> bf16 converts (G13: vectorized) ----------
__global__ __launch_bounds__(256) void cvt_qkv(const float* __restrict__ Q,
                                               const float* __restrict__ K,
                                               const float* __restrict__ V,
                                               __bf16* __restrict__ Qb,
                                               __bf16* __restrict__ Kb,
                                               __bf16* __restrict__ Vb) {
  const float* s = blockIdx.y == 0 ? Q : blockIdx.y == 1 ? K : V;
  __bf16* d = blockIdx.y == 0 ? Qb : blockIdx.y == 1 ? Kb : Vb;
  size_t i = ((size_t)blockIdx.x * 256 + threadIdx.x) * 8;
  float4 a = *(const float4*)(s + i);
  float4 c = *(const float4*)(s + i + 4);
  bf16x8 r;
  r[0] = (__bf16)a.x; r[1] = (__bf16)a.y; r[2] = (__bf16)a.z; r[3] = (__bf16)a.w;
  r[4] = (__bf16)c.x; r[5] = (__bf16)c.y; r[6] = (__bf16)c.z; r[7] = (__bf16)c.w;
  *(bf16x8*)(d + i) = r;
}

__global__ __launch_bounds__(256) void cvt_w(const float* __restrict__ W0,
                                             const float* __restrict__ W1,
                                             const float* __restrict__ W2,
                                             const float* __restrict__ W3,
                                             __bf16* __restrict__ O0,
                                             __bf16* __restrict__ O1,
                                             __bf16* __restrict__ O2,
                                             __bf16* __restrict__ O3) {
  const float* s = blockIdx.y == 0 ? W0 : blockIdx.y == 1 ? W1 : blockIdx.y == 2 ? W2 : W3;
  __bf16* d = blockIdx.y == 0 ? O0 : blockIdx.y == 1 ? O1 : blockIdx.y == 2 ? O2 : O3;
  size_t i = ((size_t)blockIdx.x * 256 + threadIdx.x) * 8;
  float4 a = *(const float4*)(s + i);
  float4 c = *(const float4*)(s + i + 4);
  bf16x8 r;
  r[0] = (__bf16)a.x; r[1] = (__bf16)a.y; r[2] = (__bf16)a.z; r[3] = (__bf16)a.w;
  r[4] = (__bf16)c.x; r[5] = (__bf16)c.y; r[6] = (__bf16)c.z; r[7] = (__bf16)c.w;
  *(bf16x8*)(d + i) = r;
}

// ---------- mask -> bitmask (32 u64 per row) ----------
__global__ __launch_bounds__(256) void pack_mask_k(const int* __restrict__ mask,
                                                   unsigned long long* __restrict__ bits) {
  int e = blockIdx.x * 256 + threadIdx.x;
  unsigned long long b = __ballot(mask[e] != 0);
  if ((threadIdx.x & 63) == 0) bits[e >> 6] = b;
}

// ---------- GEMM, BK=64, T2-swizzled LDS, double-buffered 1-barrier pipeline ----------
// C[m][n] = alpha * sum_k A[m,k]*B[n,k], K=768
// MODE 0: bf16 row-major (alpha)   MODE 1: khF fragment-major
// MODE 2: vTF fragment-major perm  MODE 3: f32 row-major
template <int MODE, typename CT>
__device__ __forceinline__ void gemm_body(const __bf16* __restrict__ A,
                                          const __bf16* __restrict__ B,
                                          CT* __restrict__ C, int N, int row0,
                                          int col0, float alpha, __bf16* As,
                                          __bf16* Bs) {
  const int K = EMBED;
  const int NIT = K / 64;  // 12
  const int tid = threadIdx.x;
  const int lane = tid & 63;
  const int wave = tid >> 6;
  const int wr = wave >> 1, wc = wave & 1;
  const int l15 = lane & 15, g = lane >> 4;
  f32x4 acc[4][4] = {};

  // staging: LDS row-major [128][64] bf16; gload_lds writes linearly, so the
  // XOR col-swizzle is applied to the GLOBAL source (rule #21) and on reads.
  const int srow = tid >> 3;                 // 0..31
  const int scol8 = (tid & 7) ^ (srow & 7);  // pre-swizzled source col-group
  const __bf16* aS = A + (size_t)(row0 + srow) * K + scol8 * 8;
  const __bf16* bS = B + (size_t)(col0 + srow) * K + scol8 * 8;
  __bf16* aL = As + wave * 512;  // wave covers 8 rows per issue
  __bf16* bL = Bs + wave * 512;

  auto stage = [&](int buf, int k0) {
#pragma unroll
    for (int q = 0; q < 4; ++q) {
      gload_lds16(aS + k0 + (size_t)(q * 32) * K, aL + buf * 8192 + q * 2048);
      gload_lds16(bS + k0 + (size_t)(q * 32) * K, bL + buf * 8192 + q * 2048);
    }
  };

  stage(0, 0);  // prologue
#pragma unroll 2
  for (int it = 0; it < NIT; ++it) {
    const int c = it & 1;
    phase_barrier();  // buf c ready; all prior ds_reads consumed
    if (it + 1 < NIT) stage(1 - c, (it + 1) * 64);  // prefetch overlaps compute
    const __bf16* Asc = As + c * 8192;
    const __bf16* Bsc = Bs + c * 8192;
    bf16x8 af[2][4], bfr[2][4];
#pragma unroll
    for (int i = 0; i < 4; ++i) {
      int row = wr * 64 + i * 16 + l15;
#pragma unroll
      for (int kk = 0; kk < 2; ++kk)
        af[kk][i] =
            *(const bf16x8*)(Asc + row * 64 + ((kk * 4 + g) ^ (row & 7)) * 8);
    }
#pragma unroll
    for (int j = 0; j < 4; ++j) {
      int row = wc * 64 + j * 16 + l15;
#pragma unroll
      for (int kk = 0; kk < 2; ++kk)
        bfr[kk][j] =
            *(const bf16x8*)(Bsc + row * 64 + ((kk * 4 + g) ^ (row & 7)) * 8);
    }
    __builtin_amdgcn_s_setprio(1);
#pragma unroll
    for (int kk = 0; kk < 2; ++kk)
#pragma unroll
      for (int i = 0; i < 4; ++i)
#pragma unroll
        for (int j = 0; j < 4; ++j)
          acc[i][j] = __builtin_amdgcn_mfma_f32_16x16x32_bf16(
              af[kk][i], bfr[kk][j], acc[i][j], 0, 0, 0);
    __builtin_amdgcn_s_setprio(0);
  }
  // C/D layout: col=lane&15, row=(lane>>4)*4+reg  [m89]
#pragma unroll
  for (int i = 0; i < 4; ++i)
#pragma unroll
    for (int j = 0; j < 4; ++j) {
#pragma unroll
      for (int r = 0; r < 4; ++r) {
        float val = alpha * acc[i][j][r];
        int mrow = row0 + wr * 64 + i * 16 + g * 4 + r;   // A-row
        int ncol = col0 + wc * 64 + j * 16 + l15;          // B-row
        if (MODE == 0 || MODE == 3) {
          C[(size_t)mrow * N + ncol] = (CT)val;
        } else if (MODE == 1) {
          // A-rows = tokens, B-rows = features -> khF fragment-major
          int tok = mrow, fcol = ncol;
          int h = fcol >> 6, d = fcol & 63;
          int bh = (tok >> 11) * NHEAD + h;
          int t = (tok >> 6) & 31, kk = tok & 63;
          size_t idx = ((size_t)bh * 32 + t) * 4096 +
                       ((((kk >> 4) * 2 + (d >> 5)) * 64 + ((d >> 3) & 3) * 16 +
                         (kk & 15)) *
                            8 +
                        (d & 7));
          C[idx] = (CT)val;
        } else {
          // MODE 2: A-rows = features, B-rows = tokens -> vTF fragment-major, kv-permuted
          int fr = mrow, tok = ncol;
          int h = fr >> 6, d = fr & 63;
          int dt = d >> 4, l15c = d & 15;
          int bh = (tok >> 11) * NHEAD + h;
          int t = (tok >> 6) & 31, kk = tok & 63;
          int pc = (kk & 32) | ((kk & 12) << 1) | ((kk & 16) >> 2) | (kk & 3);
          int ks = pc >> 5, Gb = (pc >> 3) & 3, e = pc & 7;
          size_t idx = ((size_t)bh * 32 + t) * 4096 +
                       (((ks * 4 + dt) * 64 + Gb * 16 + l15c) * 8 + e);
          C[idx] = (CT)val;
        }
      }
    }
}

__global__ __launch_bounds__(256) void gemm_qkv(
    const __bf16* __restrict__ Qb, const __bf16* __restrict__ Kb,
    const __bf16* __restrict__ Vb, const __bf16* __restrict__ Wqb,
    const __bf16* __restrict__ Wkb, const __bf16* __restrict__ Wvb,
    __bf16* __restrict__ qh, __bf16* __restrict__ khF, __bf16* __restrict__ vTF) {
  __shared__ __align__(16) __bf16 As[2 * 128 * 64];
  __shared__ __align__(16) __bf16 Bs[2 * 128 * 64];
  if (blockIdx.z == 0)
    gemm_body<0, __bf16>(Qb, Wqb, qh, EMBED, blockIdx.x * 128,
                         blockIdx.y * 128, SCALE_LOG2, As, Bs);
  else if (blockIdx.z == 1)
    gemm_body<1, __bf16>(Kb, Wkb, khF, 0, blockIdx.x * 128, blockIdx.y * 128,
                         1.f, As, Bs);
  else
    gemm_body<2, __bf16>(Wvb, Vb, vTF, 0, blockIdx.y * 128, blockIdx.x * 128,
                         1.f, As, Bs);
}

__global__ __launch_bounds__(256) void gemm_out(const __bf16* __restrict__ AO,
                                                const __bf16* __restrict__ Wob,
                                                float* __restrict__ out) {
  __shared__ __align__(16) __bf16 As[2 * 128 * 64];
  __shared__ __align__(16) __bf16 Bs[2 * 128 * 64];
  gemm_body<3, float>(AO, Wob, out, EMBED, blockIdx.x * 128, blockIdx.y * 128,
                      1.f, As, Bs);
}

// ---------- flash attention: pure-register streaming, NO LDS, NO barriers ----------
// khF/vTF fragment-major => wave K/V loads are lane-contiguous 1KB global loads.
// Each wave streams its 8 tiles independently; compiler pipelines via vmcnt.
__global__ __launch_bounds__(256, 4) void flash_attn(
    const __bf16* __restrict__ qh, const __bf16* __restrict__ khF,
    const __bf16* __restrict__ vTF, const unsigned long long* __restrict__ mbits,
    float* __restrict__ Opart, float* __restrict__ lpart) {
  // XCD-aware bijective swizzle: 1536 blocks = 8 XCDs x 192
  int lin = blockIdx.x + 16 * (blockIdx.y + NBH * blockIdx.z);
  int wid = (lin & 7) * 192 + (lin >> 3);
  int qb = wid & 15;
  int rest = wid >> 4;  // 0..95
  int bh = rest % NBH;
  int z = rest / NBH;

  const int tid = threadIdx.x;
  const int lane = tid & 63, w = tid >> 6;
  const int l15 = lane & 15, G = lane >> 4;
  const int b = bh / NHEAD, h = bh % NHEAD;
  const int qrow0 = qb * 128 + w * 32;

  bf16x8 qf[2][2];
#pragma unroll
  for (int qg = 0; qg < 2; ++qg) {
    const __bf16* qptr =
        qh + ((size_t)b * SEQ + qrow0 + qg * 16 + l15) * EMBED + h * HDIM + G * 8;
    qf[qg][0] = *(const bf16x8*)qptr;
    qf[qg][1] = *(const bf16x8*)(qptr + 32);
  }
  const u32x4 onesr = {0x3F803F80u, 0x3F803F80u, 0x3F803F80u, 0x3F803F80u};
  const bf16x8 ones = __builtin_bit_cast(bf16x8, onesr);

  f32x4 o[2][4] = {};  // o[qg][dt][r] = O[q=l15][d = dt*16 + G*4 + r] (unnormalized)
  f32x4 ol[2] = {};    // ol[qg][*] = l[q=l15] via ones-A MFMA

  // fragment-major tile bases; lane's 16B slice
  const __bf16* kb =
      khF + ((size_t)bh * 32 + z * TILES_PER_SPLIT) * 4096 + lane * 8;
  const __bf16* vb =
      vTF + ((size_t)bh * 32 + z * TILES_PER_SPLIT) * 4096 + lane * 8;
  const unsigned long long* mrow0 =
      mbits + (size_t)(qrow0 + l15) * 32 + z * TILES_PER_SPLIT;
  const unsigned long long* mrow1 = mrow0 + 16 * 32;

#pragma unroll 2
  for (int tt = 0; tt < TILES_PER_SPLIT; ++tt) {
    const __bf16* kt = kb + (size_t)tt * 4096;
    const __bf16* vt = vb + (size_t)tt * 4096;
    unsigned long long mb0 = mrow0[tt], mb1 = mrow1[tt];

    // S^T per q-group: lane holds S[q=l15][kv = jj*16 + G*4 + r]
    f32x4 s[2][4];
#pragma unroll
    for (int jj = 0; jj < 4; ++jj) {
      bf16x8 kf0 = *(const bf16x8*)(kt + (jj * 2 + 0) * 512);
      bf16x8 kf1 = *(const bf16x8*)(kt + (jj * 2 + 1) * 512);
#pragma unroll
      for (int qg = 0; qg < 2; ++qg) {
        f32x4 zz = {};
        zz = __builtin_amdgcn_mfma_f32_16x16x32_bf16(kf0, qf[qg][0], zz, 0, 0, 0);
        zz = __builtin_amdgcn_mfma_f32_16x16x32_bf16(kf1, qf[qg][1], zz, 0, 0, 0);
        s[qg][jj] = zz;
      }
    }

    // no-max softmax: p = exp2(logit) & signmask(bit)  (masked -> 0.0f)
    unsigned pfw[2][2][4];
#pragma unroll
    for (int qg = 0; qg < 2; ++qg) {
      unsigned long long mb = qg == 0 ? mb0 : mb1;
      unsigned mlo = ((unsigned)mb) >> (G * 4);
      unsigned mhi = ((unsigned)(mb >> 32)) >> (G * 4);
#pragma unroll
      for (int jj = 0; jj < 4; ++jj) {
        unsigned bits = (jj < 2 ? mlo : mhi) >> ((jj & 1) * 16);
#pragma unroll
        for (int r = 0; r < 4; ++r) {
          float p = __builtin_amdgcn_exp2f(s[qg][jj][r]);
          int sm = ((int)(bits << (31 - r))) >> 31;  // 0 or -1
          s[qg][jj][r] = __builtin_bit_cast(
              float, __builtin_bit_cast(unsigned, p) & (unsigned)sm);
        }
      }
      // pack P fragments (order matches vTF's kv permutation)
#pragma unroll
      for (int ks = 0; ks < 2; ++ks) {
        pfw[qg][ks][0] = pack2(s[qg][2 * ks][0], s[qg][2 * ks][1]);
        pfw[qg][ks][1] = pack2(s[qg][2 * ks][2], s[qg][2 * ks][3]);
        pfw[qg][ks][2] = pack2(s[qg][2 * ks + 1][0], s[qg][2 * ks + 1][1]);
        pfw[qg][ks][3] = pack2(s[qg][2 * ks + 1][2], s[qg][2 * ks + 1][3]);
      }
    }
    // PV + l accumulation: V fragments streamed from global (L2)
#pragma unroll
    for (int ks = 0; ks < 2; ++ks) {
      u32x4 p0 = {pfw[0][ks][0], pfw[0][ks][1], pfw[0][ks][2], pfw[0][ks][3]};
      u32x4 p1 = {pfw[1][ks][0], pfw[1][ks][1], pfw[1][ks][2], pfw[1][ks][3]};
      bf16x8 pf0 = __builtin_bit_cast(bf16x8, p0);
      bf16x8 pf1 = __builtin_bit_cast(bf16x8, p1);
      ol[0] = __builtin_amdgcn_mfma_f32_16x16x32_bf16(ones, pf0, ol[0], 0, 0, 0);
      ol[1] = __builtin_amdgcn_mfma_f32_16x16x32_bf16(ones, pf1, ol[1], 0, 0, 0);
#pragma unroll
      for (int dt = 0; dt < 4; ++dt) {
        bf16x8 vf = *(const bf16x8*)(vt + (ks * 4 + dt) * 512);
        o[0][dt] = __builtin_amdgcn_mfma_f32_16x16x32_bf16(vf, pf0, o[0][dt], 0, 0, 0);
        o[1][dt] = __builtin_amdgcn_mfma_f32_16x16x32_bf16(vf, pf1, o[1][dt], 0, 0, 0);
      }
    }
  }
  // write partials
#pragma unroll
  for (int qg = 0; qg < 2; ++qg) {
    int qrow = qrow0 + qg * 16 + l15;
    size_t obase = (((size_t)z * NBH + bh) * SEQ + qrow) * HDIM;
    f32x4* op = (f32x4*)(Opart + obase);
#pragma unroll
    for (int dt = 0; dt < 4; ++dt) op[dt * 4 + G] = o[qg][dt];
    if (G == 0)
      lpart[((size_t)z * NBH + bh) * SEQ + qrow] = ol[qg][0];
  }
}

// ---------- combine the kv-splits -> AO bf16 (plain sums: m == 0 everywhere) ----------
__global__ __launch_bounds__(256) void combine(const float* __restrict__ Opart,
                                               const float* __restrict__ lpart,
                                               __bf16* __restrict__ AO) {
  int idx = blockIdx.x * 256 + threadIdx.x;  // over NBH*SEQ*16
  int bhq = idx >> 4, dq = idx & 15;
  int bh = bhq >> 11, q = bhq & (SEQ - 1);
  const f32x4* Ov = (const f32x4*)Opart;
  float lsum = 0.f;
  float r0 = 0.f, r1 = 0.f, r2 = 0.f, r3 = 0.f;
#pragma unroll
  for (int s = 0; s < NSPLIT; ++s) {
    lsum += lpart[(size_t)s * NBH * SEQ + bhq];
    f32x4 a = Ov[(size_t)s * NBH * SEQ * 16 + (size_t)bhq * 16 + dq];
    r0 += a[0];
    r1 += a[1];
    r2 += a[2];
    r3 += a[3];
  }
  float inv = 1.f / lsum;
  int bb = bh / NHEAD, hh = bh % NHEAD;
  unsigned* dst =
      (unsigned*)(AO + ((size_t)bb * SEQ + q) * EMBED + hh * HDIM + dq * 4);
  dst[0] = pack2(r0 * inv, r1 * inv);
  dst[1] = pack2(r2 * inv, r3 * inv);
}

// ---------- launch ----------
extern "C" void kernel_launch(void* const* d_in, const int* in_sizes, int n_in,
                              void* d_out, int out_size, void* d_ws,
                              size_t ws_size, hipStream_t stream) {
  const float* Q = (const float*)d_in[0];
  const float* K = (const float*)d_in[1];
  const float* V = (const float*)d_in[2];
  const int* mask = (const int*)d_in[3];
  const float* Wq = (const float*)d_in[4];
  const float* Wk = (const float*)d_in[5];
  const float* Wv = (const float*)d_in[6];
  const float* Wo = (const float*)d_in[7];
  float* out = (float*)d_out;

  char* ws = (char*)d_ws;
  const size_t ACT = (size_t)NTOK * EMBED * 2;   // 6.29 MB bf16
  const size_t WMT = (size_t)EMBED * EMBED * 2;  // 1.18 MB bf16
  const size_t OPART_B = (size_t)NSPLIT * NBH * SEQ * HDIM * 4;  // 50.3 MB

  // Opart overlays the dead-after-gemm_qkv region {Qb,Kb,Vb,Wqb,Wkb,Wvb} (22.4 MB)
  float* Opart = (float*)ws;
  __bf16* Qb = (__bf16*)ws;
  __bf16* Kb = (__bf16*)(ws + ACT);
  __bf16* Vb = (__bf16*)(ws + 2 * ACT);
  __bf16* Wqb = (__bf16*)(ws + 3 * ACT);
  __bf16* Wkb = (__bf16*)(ws + 3 * ACT + WMT);
  __bf16* Wvb = (__bf16*)(ws + 3 * ACT + 2 * WMT);
  size_t off = OPART_B;
  auto alloc = [&](size_t bytes) {
    char* p = ws + off;
    off += (bytes + 255) & ~(size_t)255;
    return p;
  };
  __bf16* Wob = (__bf16*)alloc(WMT);
  __bf16* qh = (__bf16*)alloc(ACT);
  __bf16* khF = (__bf16*)alloc(ACT);
  __bf16* vTF = (__bf16*)alloc(ACT);
  __bf16* AO = (__bf16*)alloc(ACT);
  unsigned long long* mbits =
      (unsigned long long*)alloc((size_t)SEQ * (SEQ / 64) * 8);       // 512 KB
  float* lpart = (float*)alloc((size_t)NSPLIT * NBH * SEQ * 4);       // 786 KB

  cvt_qkv<<<dim3(NTOK * EMBED / 2048, 3), 256, 0, stream>>>(Q, K, V, Qb, Kb, Vb);
  cvt_w<<<dim3(EMBED * EMBED / 2048, 4), 256, 0, stream>>>(Wq, Wk, Wv, Wo, Wqb,
                                                           Wkb, Wvb, Wob);
  pack_mask_k<<<dim3(SEQ * SEQ / 256), 256, 0, stream>>>(mask, mbits);
  gemm_qkv<<<dim3(NTOK / 128, EMBED / 128, 3), 256, 0, stream>>>(
      Qb, Kb, Vb, Wqb, Wkb, Wvb, qh, khF, vTF);
  flash_attn<<<dim3(SEQ / 128, NBH, NSPLIT), 256, 0, stream>>>(qh, khF, vTF,
                                                               mbits, Opart,
                                                               lpart);
  combine<<<dim3(NBH * SEQ * 16 / 256), 256, 0, stream>>>(Opart, lpart, AO);
  gemm_out<<<dim3(NTOK / 128, EMBED / 128), 256, 0, stream>>>(AO, Wob, out);
  (void)in_sizes; (void)n_in; (void)out_size; (void)ws_size;
}

// Round 15
// 127.314 us; speedup vs baseline: 1.1025x; 1.1025x over previous
//
#include <hip/hip_runtime.h>
#include <cmath>

typedef __bf16 bf16x8 __attribute__((ext_vector_type(8)));
typedef float f32x4 __attribute__((ext_vector_type(4)));
typedef unsigned int u32x4 __attribute__((ext_vector_type(4)));

#define SEQ 2048
#define EMBED 768
#define NHEAD 12
#define HDIM 64
#define NTOK 4096   // BS*SEQ
#define NBH 24      // BS*NHEAD
#define NSPLIT 2
#define TILES_PER_SPLIT (SEQ / 64 / NSPLIT)  // 16
// base-2 logits: fold log2(e)/sqrt(768) into the q projection
#define SCALE_LOG2 (1.4426950408889634f * 0.036084391824351615f)

// ---------- helpers ----------
__device__ __forceinline__ void gload_lds16(const __bf16* g, __bf16* l) {
  __builtin_amdgcn_global_load_lds(
      (const __attribute__((address_space(1))) void*)g,
      (__attribute__((address_space(3))) void*)l, 16, 0, 0);
}

__device__ __forceinline__ unsigned pack2(float a, float b) {
  unsigned short lo = __builtin_bit_cast(unsigned short, (__bf16)a);
  unsigned short hi = __builtin_bit_cast(unsigned short, (__bf16)b);
  return (unsigned)lo | ((unsigned)hi << 16);
}

// one barrier per pipeline phase (flash): drain my DMA, sync, pin the scheduler
__device__ __forceinline__ void phase_barrier() {
  asm volatile("s_waitcnt vmcnt(0)" ::: "memory");
  __builtin_amdgcn_s_barrier();
  __builtin_amdgcn_sched_barrier(0);
}

// ---------- fused prep: fp32->bf16 converts (G13-vectorized) + mask bitpack ----------
#define NB_A (NTOK * EMBED / 2048)   // 1536 blocks per activation tensor
#define NB_W (EMBED * EMBED / 2048)  // 288 blocks per weight
#define NB_M (SEQ * SEQ / 256)       // 16384 blocks for mask
__global__ __launch_bounds__(256) void prep(
    const float* __restrict__ Q, const float* __restrict__ K,
    const float* __restrict__ V, const float* __restrict__ Wq,
    const float* __restrict__ Wk, const float* __restrict__ Wv,
    const float* __restrict__ Wo, const int* __restrict__ mask,
    __bf16* __restrict__ Qb, __bf16* __restrict__ Kb, __bf16* __restrict__ Vb,
    __bf16* __restrict__ Wqb, __bf16* __restrict__ Wkb,
    __bf16* __restrict__ Wvb, __bf16* __restrict__ Wob,
    unsigned long long* __restrict__ bits) {
  int bid = blockIdx.x;
  if (bid < 3 * NB_A + 4 * NB_W) {
    const float* s;
    __bf16* d;
    int sub;
    if (bid < 3 * NB_A) {
      int which = bid / NB_A;
      sub = bid % NB_A;
      s = which == 0 ? Q : which == 1 ? K : V;
      d = which == 0 ? Qb : which == 1 ? Kb : Vb;
    } else {
      int r = bid - 3 * NB_A;
      int which = r / NB_W;
      sub = r % NB_W;
      s = which == 0 ? Wq : which == 1 ? Wk : which == 2 ? Wv : Wo;
      d = which == 0 ? Wqb : which == 1 ? Wkb : which == 2 ? Wvb : Wob;
    }
    size_t i = ((size_t)sub * 256 + threadIdx.x) * 8;
    float4 a = *(const float4*)(s + i);
    float4 c = *(const float4*)(s + i + 4);
    bf16x8 r;
    r[0] = (__bf16)a.x; r[1] = (__bf16)a.y; r[2] = (__bf16)a.z; r[3] = (__bf16)a.w;
    r[4] = (__bf16)c.x; r[5] = (__bf16)c.y; r[6] = (__bf16)c.z; r[7] = (__bf16)c.w;
    *(bf16x8*)(d + i) = r;
  } else {
    int e = (bid - (3 * NB_A + 4 * NB_W)) * 256 + threadIdx.x;
    unsigned long long b = __ballot(mask[e] != 0);
    if ((threadIdx.x & 63) == 0) bits[e >> 6] = b;
  }
}

// ---------- GEMM, BK=32, 2-barrier m97 structure (max residency at small K) ----------
// C[m][n] = alpha * sum_k A[m,k]*B[n,k], K=768
// MODE 0: bf16 row-major (alpha)   MODE 1: khF fragment-major
// MODE 2: vTF fragment-major perm  MODE 3: f32 row-major
template <int MODE, typename CT>
__device__ __forceinline__ void gemm_body(const __bf16* __restrict__ A,
                                          const __bf16* __restrict__ B,
                                          CT* __restrict__ C, int N, int row0,
                                          int col0, float alpha, __bf16* As,
                                          __bf16* Bs) {
  const int K = EMBED;
  const int tid = threadIdx.x;
  const int lane = tid & 63;
  const int wave = tid >> 6;
  const int wr = wave >> 1, wc = wave & 1;
  const int l15 = lane & 15, g = lane >> 4;
  f32x4 acc[4][4] = {};

  // staging: thread t covers LDS bytes [t*16, t*16+16) of an 8KB tile ([128][32] bf16)
  const __bf16* aS = A + (size_t)(row0 + (tid >> 2)) * K + (tid & 3) * 8;
  const __bf16* bS = B + (size_t)(col0 + (tid >> 2)) * K + (tid & 3) * 8;
  __bf16* aL = As + wave * 512;
  __bf16* bL = Bs + wave * 512;

  for (int k0 = 0; k0 < K; k0 += 32) {
    __syncthreads();  // previous iter's ds_reads done before overwrite
    gload_lds16(aS + k0, aL);
    gload_lds16(aS + k0 + (size_t)64 * K, aL + 2048);
    gload_lds16(bS + k0, bL);
    gload_lds16(bS + k0 + (size_t)64 * K, bL + 2048);
    __syncthreads();  // staging visible
    bf16x8 af[4], bfr[4];
#pragma unroll
    for (int i = 0; i < 4; ++i)
      af[i] = *(const bf16x8*)(As + (wr * 64 + i * 16 + l15) * 32 + g * 8);
#pragma unroll
    for (int j = 0; j < 4; ++j)
      bfr[j] = *(const bf16x8*)(Bs + (wc * 64 + j * 16 + l15) * 32 + g * 8);
    __builtin_amdgcn_s_setprio(1);
#pragma unroll
    for (int i = 0; i < 4; ++i)
#pragma unroll
      for (int j = 0; j < 4; ++j)
        acc[i][j] = __builtin_amdgcn_mfma_f32_16x16x32_bf16(af[i], bfr[j],
                                                            acc[i][j], 0, 0, 0);
    __builtin_amdgcn_s_setprio(0);
  }
  // C/D layout: col=lane&15, row=(lane>>4)*4+reg  [m89]
#pragma unroll
  for (int i = 0; i < 4; ++i)
#pragma unroll
    for (int j = 0; j < 4; ++j) {
#pragma unroll
      for (int r = 0; r < 4; ++r) {
        float val = alpha * acc[i][j][r];
        int mrow = row0 + wr * 64 + i * 16 + g * 4 + r;   // A-row
        int ncol = col0 + wc * 64 + j * 16 + l15;          // B-row
        if (MODE == 0 || MODE == 3) {
          C[(size_t)mrow * N + ncol] = (CT)val;
        } else if (MODE == 1) {
          // A-rows = tokens, B-rows = features -> khF fragment-major
          int tok = mrow, fcol = ncol;
          int h = fcol >> 6, d = fcol & 63;
          int bh = (tok >> 11) * NHEAD + h;
          int t = (tok >> 6) & 31, kk = tok & 63;
          size_t idx = ((size_t)bh * 32 + t) * 4096 +
                       ((((kk >> 4) * 2 + (d >> 5)) * 64 + ((d >> 3) & 3) * 16 +
                         (kk & 15)) *
                            8 +
                        (d & 7));
          C[idx] = (CT)val;
        } else {
          // MODE 2: A-rows = features, B-rows = tokens -> vTF fragment-major, kv-permuted
          int fr = mrow, tok = ncol;
          int h = fr >> 6, d = fr & 63;
          int dt = d >> 4, l15c = d & 15;
          int bh = (tok >> 11) * NHEAD + h;
          int t = (tok >> 6) & 31, kk = tok & 63;
          int pc = (kk & 32) | ((kk & 12) << 1) | ((kk & 16) >> 2) | (kk & 3);
          int ks = pc >> 5, Gb = (pc >> 3) & 3, e = pc & 7;
          size_t idx = ((size_t)bh * 32 + t) * 4096 +
                       (((ks * 4 + dt) * 64 + Gb * 16 + l15c) * 8 + e);
          C[idx] = (CT)val;
        }
      }
    }
}

__global__ __launch_bounds__(256) void gemm_qkv(
    const __bf16* __restrict__ Qb, const __bf16* __restrict__ Kb,
    const __bf16* __restrict__ Vb, const __bf16* __restrict__ Wqb,
    const __bf16* __restrict__ Wkb, const __bf16* __restrict__ Wvb,
    __bf16* __restrict__ qh, __bf16* __restrict__ khF, __bf16* __restrict__ vTF) {
  __shared__ __align__(16) __bf16 As[128 * 32];
  __shared__ __align__(16) __bf16 Bs[128 * 32];
  if (blockIdx.z == 0)
    gemm_body<0, __bf16>(Qb, Wqb, qh, EMBED, blockIdx.x * 128,
                         blockIdx.y * 128, SCALE_LOG2, As, Bs);
  else if (blockIdx.z == 1)
    gemm_body<1, __bf16>(Kb, Wkb, khF, 0, blockIdx.x * 128, blockIdx.y * 128,
                         1.f, As, Bs);
  else
    gemm_body<2, __bf16>(Wvb, Vb, vTF, 0, blockIdx.y * 128, blockIdx.x * 128,
                         1.f, As, Bs);
}

__global__ __launch_bounds__(256) void gemm_out(const __bf16* __restrict__ AO,
                                                const __bf16* __restrict__ Wob,
                                                float* __restrict__ out) {
  __shared__ __align__(16) __bf16 As[128 * 32];
  __shared__ __align__(16) __bf16 Bs[128 * 32];
  gemm_body<3, float>(AO, Wob, out, EMBED, blockIdx.x * 128, blockIdx.y * 128,
                      1.f, As, Bs);
}

// ---------- flash attention: R9 config (4-wave, dbuf 1-barrier, KV-split=2) ----------
__global__ __launch_bounds__(256, 4) void flash_attn(
    const __bf16* __restrict__ qh, const __bf16* __restrict__ khF,
    const __bf16* __restrict__ vTF, const unsigned long long* __restrict__ mbits,
    float* __restrict__ Opart, float* __restrict__ lpart) {
  __shared__ __align__(16) __bf16 Ks[2][4096];  // 2 x 8KB frag-major K tile
  __shared__ __align__(16) __bf16 Vs[2][4096];  // 2 x 8KB frag-major V tile
  // XCD-aware bijective swizzle: 768 blocks = 8 XCDs x 96
  int lin = blockIdx.x + 16 * (blockIdx.y + NBH * blockIdx.z);
  int wid = (lin & 7) * 96 + (lin >> 3);
  int qb = wid & 15;
  int rest = wid >> 4;  // 0..47
  int bh = rest % NBH;
  int z = rest / NBH;

  const int tid = threadIdx.x;
  const int lane = tid & 63, w = tid >> 6;
  const int l15 = lane & 15, G = lane >> 4;
  const int b = bh / NHEAD, h = bh % NHEAD;
  const int qrow0 = qb * 128 + w * 32;

  bf16x8 qf[2][2];
#pragma unroll
  for (int qg = 0; qg < 2; ++qg) {
    const __bf16* qptr =
        qh + ((size_t)b * SEQ + qrow0 + qg * 16 + l15) * EMBED + h * HDIM + G * 8;
    qf[qg][0] = *(const bf16x8*)qptr;
    qf[qg][1] = *(const bf16x8*)(qptr + 32);
  }
  const u32x4 onesr = {0x3F803F80u, 0x3F803F80u, 0x3F803F80u, 0x3F803F80u};
  const bf16x8 ones = __builtin_bit_cast(bf16x8, onesr);

  f32x4 o[2][4] = {};  // o[qg][dt][r] = O[q=l15][d = dt*16 + G*4 + r] (unnormalized)
  f32x4 ol[2] = {};    // ol[qg][*] = l[q=l15] via ones-A MFMA

  const __bf16* ktile =
      khF + ((size_t)bh * 32 + z * TILES_PER_SPLIT) * 4096 + tid * 8;
  const __bf16* vtile =
      vTF + ((size_t)bh * 32 + z * TILES_PER_SPLIT) * 4096 + tid * 8;
  const unsigned long long* mrow0 =
      mbits + (size_t)(qrow0 + l15) * 32 + z * TILES_PER_SPLIT;
  const unsigned long long* mrow1 = mrow0 + 16 * 32;

  // prologue: stage tile 0 into buf 0, load its mask words
  gload_lds16(ktile, &Ks[0][0] + w * 512);
  gload_lds16(ktile + 2048, &Ks[0][0] + w * 512 + 2048);
  gload_lds16(vtile, &Vs[0][0] + w * 512);
  gload_lds16(vtile + 2048, &Vs[0][0] + w * 512 + 2048);
  unsigned long long mb0 = mrow0[0], mb1 = mrow1[0];

#pragma unroll 2
  for (int tt = 0; tt < TILES_PER_SPLIT; ++tt) {
    const int c = tt & 1;
    phase_barrier();  // buf c ready; all prior ds_reads consumed
    unsigned long long nmb0 = 0, nmb1 = 0;
    if (tt + 1 < TILES_PER_SPLIT) {  // prefetch tile tt+1 under this compute
      const __bf16* kt = ktile + (size_t)(tt + 1) * 4096;
      const __bf16* vt = vtile + (size_t)(tt + 1) * 4096;
      __bf16* kd = &Ks[1 - c][0] + w * 512;
      __bf16* vd = &Vs[1 - c][0] + w * 512;
      gload_lds16(kt, kd);
      gload_lds16(kt + 2048, kd + 2048);
      gload_lds16(vt, vd);
      gload_lds16(vt + 2048, vd + 2048);
      nmb0 = mrow0[tt + 1];
      nmb1 = mrow1[tt + 1];
    }

    // S^T per q-group: lane holds S[q=l15][kv = jj*16 + G*4 + r]
    f32x4 s[2][4];
    __builtin_amdgcn_s_setprio(1);
#pragma unroll
    for (int jj = 0; jj < 4; ++jj) {
      bf16x8 kf0 = *(const bf16x8*)(&Ks[c][0] + (jj * 2 + 0) * 512 + lane * 8);
      bf16x8 kf1 = *(const bf16x8*)(&Ks[c][0] + (jj * 2 + 1) * 512 + lane * 8);
#pragma unroll
      for (int qg = 0; qg < 2; ++qg) {
        f32x4 zz = {};
        zz = __builtin_amdgcn_mfma_f32_16x16x32_bf16(kf0, qf[qg][0], zz, 0, 0, 0);
        zz = __builtin_amdgcn_mfma_f32_16x16x32_bf16(kf1, qf[qg][1], zz, 0, 0, 0);
        s[qg][jj] = zz;
      }
    }
    __builtin_amdgcn_s_setprio(0);

    // no-max softmax: p = exp2(logit) & signmask(bit)  (masked -> 0.0f)
    unsigned pfw[2][2][4];
#pragma unroll
    for (int qg = 0; qg < 2; ++qg) {
      unsigned long long mb = qg == 0 ? mb0 : mb1;
      unsigned mlo = ((unsigned)mb) >> (G * 4);
      unsigned mhi = ((unsigned)(mb >> 32)) >> (G * 4);
#pragma unroll
      for (int jj = 0; jj < 4; ++jj) {
        unsigned bits = (jj < 2 ? mlo : mhi) >> ((jj & 1) * 16);
#pragma unroll
        for (int r = 0; r < 4; ++r) {
          float p = __builtin_amdgcn_exp2f(s[qg][jj][r]);
          int sm = ((int)(bits << (31 - r))) >> 31;  // 0 or -1
          s[qg][jj][r] = __builtin_bit_cast(
              float, __builtin_bit_cast(unsigned, p) & (unsigned)sm);
        }
      }
      // pack P fragments (order matches vTF's kv permutation)
#pragma unroll
      for (int ks = 0; ks < 2; ++ks) {
        pfw[qg][ks][0] = pack2(s[qg][2 * ks][0], s[qg][2 * ks][1]);
        pfw[qg][ks][1] = pack2(s[qg][2 * ks][2], s[qg][2 * ks][3]);
        pfw[qg][ks][2] = pack2(s[qg][2 * ks + 1][0], s[qg][2 * ks + 1][1]);
        pfw[qg][ks][3] = pack2(s[qg][2 * ks + 1][2], s[qg][2 * ks + 1][3]);
      }
    }
    // PV + l accumulation: V fragments from LDS, shared across both q-groups
    __builtin_amdgcn_s_setprio(1);
#pragma unroll
    for (int ks = 0; ks < 2; ++ks) {
      u32x4 p0 = {pfw[0][ks][0], pfw[0][ks][1], pfw[0][ks][2], pfw[0][ks][3]};
      u32x4 p1 = {pfw[1][ks][0], pfw[1][ks][1], pfw[1][ks][2], pfw[1][ks][3]};
      bf16x8 pf0 = __builtin_bit_cast(bf16x8, p0);
      bf16x8 pf1 = __builtin_bit_cast(bf16x8, p1);
      ol[0] = __builtin_amdgcn_mfma_f32_16x16x32_bf16(ones, pf0, ol[0], 0, 0, 0);
      ol[1] = __builtin_amdgcn_mfma_f32_16x16x32_bf16(ones, pf1, ol[1], 0, 0, 0);
#pragma unroll
      for (int dt = 0; dt < 4; ++dt) {
        bf16x8 vf = *(const bf16x8*)(&Vs[c][0] + (ks * 4 + dt) * 512 + lane * 8);
        o[0][dt] = __builtin_amdgcn_mfma_f32_16x16x32_bf16(vf, pf0, o[0][dt], 0, 0, 0);
        o[1][dt] = __builtin_amdgcn_mfma_f32_16x16x32_bf16(vf, pf1, o[1][dt], 0, 0, 0);
      }
    }
    __builtin_amdgcn_s_setprio(0);
    mb0 = nmb0;
    mb1 = nmb1;
  }
  // write partials
#pragma unroll
  for (int qg = 0; qg < 2; ++qg) {
    int qrow = qrow0 + qg * 16 + l15;
    size_t obase = (((size_t)z * NBH + bh) * SEQ + qrow) * HDIM;
    f32x4* op = (f32x4*)(Opart + obase);
#pragma unroll
    for (int dt = 0; dt < 4; ++dt) op[dt * 4 + G] = o[qg][dt];
    if (G == 0)
      lpart[((size_t)z * NBH + bh) * SEQ + qrow] = ol[qg][0];
  }
}

// ---------- combine the kv-splits -> AO bf16 (plain sums: m == 0 everywhere) ----------
__global__ __launch_bounds__(256) void combine(const float* __restrict__ Opart,
                                               const float* __restrict__ lpart,
                                               __bf16* __restrict__ AO) {
  int idx = blockIdx.x * 256 + threadIdx.x;  // over NBH*SEQ*16
  int bhq = idx >> 4, dq = idx & 15;
  int bh = bhq >> 11, q = bhq & (SEQ - 1);
  const f32x4* Ov = (const f32x4*)Opart;
  float lsum = 0.f;
  float r0 = 0.f, r1 = 0.f, r2 = 0.f, r3 = 0.f;
#pragma unroll
  for (int s = 0; s < NSPLIT; ++s) {
    lsum += lpart[(size_t)s * NBH * SEQ + bhq];
    f32x4 a = Ov[(size_t)s * NBH * SEQ * 16 + (size_t)bhq * 16 + dq];
    r0 += a[0];
    r1 += a[1];
    r2 += a[2];
    r3 += a[3];
  }
  float inv = 1.f / lsum;
  int bb = bh / NHEAD, hh = bh % NHEAD;
  unsigned* dst =
      (unsigned*)(AO + ((size_t)bb * SEQ + q) * EMBED + hh * HDIM + dq * 4);
  dst[0] = pack2(r0 * inv, r1 * inv);
  dst[1] = pack2(r2 * inv, r3 * inv);
}

// ---------- launch ----------
extern "C" void kernel_launch(void* const* d_in, const int* in_sizes, int n_in,
                              void* d_out, int out_size, void* d_ws,
                              size_t ws_size, hipStream_t stream) {
  const float* Q = (const float*)d_in[0];
  const float* K = (const float*)d_in[1];
  const float* V = (const float*)d_in[2];
  const int* mask = (const int*)d_in[3];
  const float* Wq = (const float*)d_in[4];
  const float* Wk = (const float*)d_in[5];
  const float* Wv = (const float*)d_in[6];
  const float* Wo = (const float*)d_in[7];
  float* out = (float*)d_out;

  char* ws = (char*)d_ws;
  const size_t ACT = (size_t)NTOK * EMBED * 2;   // 6.29 MB bf16
  const size_t WMT = (size_t)EMBED * EMBED * 2;  // 1.18 MB bf16
  const size_t OPART_B = (size_t)NSPLIT * NBH * SEQ * HDIM * 4;  // 25.2 MB

  // Opart overlays the dead-after-gemm_qkv region {Qb,Kb,Vb,Wqb,Wkb,Wvb} (22.4 MB)
  float* Opart = (float*)ws;
  __bf16* Qb = (__bf16*)ws;
  __bf16* Kb = (__bf16*)(ws + ACT);
  __bf16* Vb = (__bf16*)(ws + 2 * ACT);
  __bf16* Wqb = (__bf16*)(ws + 3 * ACT);
  __bf16* Wkb = (__bf16*)(ws + 3 * ACT + WMT);
  __bf16* Wvb = (__bf16*)(ws + 3 * ACT + 2 * WMT);
  size_t off = OPART_B;
  auto alloc = [&](size_t bytes) {
    char* p = ws + off;
    off += (bytes + 255) & ~(size_t)255;
    return p;
  };
  __bf16* Wob = (__bf16*)alloc(WMT);
  __bf16* qh = (__bf16*)alloc(ACT);
  __bf16* khF = (__bf16*)alloc(ACT);
  __bf16* vTF = (__bf16*)alloc(ACT);
  __bf16* AO = (__bf16*)alloc(ACT);
  unsigned long long* mbits =
      (unsigned long long*)alloc((size_t)SEQ * (SEQ / 64) * 8);       // 512 KB
  float* lpart = (float*)alloc((size_t)NSPLIT * NBH * SEQ * 4);       // 393 KB

  prep<<<dim3(3 * NB_A + 4 * NB_W + NB_M), 256, 0, stream>>>(
      Q, K, V, Wq, Wk, Wv, Wo, mask, Qb, Kb, Vb, Wqb, Wkb, Wvb, Wob, mbits);
  gemm_qkv<<<dim3(NTOK / 128, EMBED / 128, 3), 256, 0, stream>>>(
      Qb, Kb, Vb, Wqb, Wkb, Wvb, qh, khF, vTF);
  flash_attn<<<dim3(SEQ / 128, NBH, NSPLIT), 256, 0, stream>>>(qh, khF, vTF,
                                                               mbits, Opart,
                                                               lpart);
  combine<<<dim3(NBH * SEQ * 16 / 256), 256, 0, stream>>>(Opart, lpart, AO);
  gemm_out<<<dim3(NTOK / 128, EMBED / 128), 256, 0, stream>>>(AO, Wob, out);
  (void)in_sizes; (void)n_in; (void)out_size; (void)ws_size;
}

// Round 16
// 113.295 us; speedup vs baseline: 1.2389x; 1.1237x over previous
//
#include <hip/hip_runtime.h>
#include <cmath>

typedef __bf16 bf16x8 __attribute__((ext_vector_type(8)));
typedef float f32x4 __attribute__((ext_vector_type(4)));
typedef unsigned int u32x4 __attribute__((ext_vector_type(4)));

#define SEQ 2048
#define EMBED 768
#define NHEAD 12
#define HDIM 64
#define NTOK 4096   // BS*SEQ
#define NBH 24      // BS*NHEAD
#define NSPLIT 2
#define TILES_PER_SPLIT (SEQ / 64 / NSPLIT)  // 16
// base-2 logits: fold log2(e)/sqrt(768) into the q projection
#define SCALE_LOG2 (1.4426950408889634f * 0.036084391824351615f)

// ---------- helpers ----------
__device__ __forceinline__ void gload_lds16(const __bf16* g, __bf16* l) {
  __builtin_amdgcn_global_load_lds(
      (const __attribute__((address_space(1))) void*)g,
      (__attribute__((address_space(3))) void*)l, 16, 0, 0);
}

__device__ __forceinline__ unsigned pack2(float a, float b) {
  unsigned short lo = __builtin_bit_cast(unsigned short, (__bf16)a);
  unsigned short hi = __builtin_bit_cast(unsigned short, (__bf16)b);
  return (unsigned)lo | ((unsigned)hi << 16);
}

// one barrier per pipeline phase: drain my DMA, sync, pin the scheduler
__device__ __forceinline__ void phase_barrier() {
  asm volatile("s_waitcnt vmcnt(0)" ::: "memory");
  __builtin_amdgcn_s_barrier();
  __builtin_amdgcn_sched_barrier(0);
}

// ---------- fused prep: fp32->bf16 converts (G13-vectorized) + mask bitpack ----------
#define NB_A (NTOK * EMBED / 2048)   // 1536 blocks per activation tensor
#define NB_W (EMBED * EMBED / 2048)  // 288 blocks per weight
#define NB_M (SEQ * SEQ / 256)       // 16384 blocks for mask
__global__ __launch_bounds__(256) void prep(
    const float* __restrict__ Q, const float* __restrict__ K,
    const float* __restrict__ V, const float* __restrict__ Wq,
    const float* __restrict__ Wk, const float* __restrict__ Wv,
    const float* __restrict__ Wo, const int* __restrict__ mask,
    __bf16* __restrict__ Qb, __bf16* __restrict__ Kb, __bf16* __restrict__ Vb,
    __bf16* __restrict__ Wqb, __bf16* __restrict__ Wkb,
    __bf16* __restrict__ Wvb, __bf16* __restrict__ Wob,
    unsigned long long* __restrict__ bits) {
  int bid = blockIdx.x;
  if (bid < 3 * NB_A + 4 * NB_W) {
    const float* s;
    __bf16* d;
    int sub;
    if (bid < 3 * NB_A) {
      int which = bid / NB_A;
      sub = bid % NB_A;
      s = which == 0 ? Q : which == 1 ? K : V;
      d = which == 0 ? Qb : which == 1 ? Kb : Vb;
    } else {
      int r = bid - 3 * NB_A;
      int which = r / NB_W;
      sub = r % NB_W;
      s = which == 0 ? Wq : which == 1 ? Wk : which == 2 ? Wv : Wo;
      d = which == 0 ? Wqb : which == 1 ? Wkb : which == 2 ? Wvb : Wob;
    }
    size_t i = ((size_t)sub * 256 + threadIdx.x) * 8;
    float4 a = *(const float4*)(s + i);
    float4 c = *(const float4*)(s + i + 4);
    bf16x8 r;
    r[0] = (__bf16)a.x; r[1] = (__bf16)a.y; r[2] = (__bf16)a.z; r[3] = (__bf16)a.w;
    r[4] = (__bf16)c.x; r[5] = (__bf16)c.y; r[6] = (__bf16)c.z; r[7] = (__bf16)c.w;
    *(bf16x8*)(d + i) = r;
  } else {
    int e = (bid - (3 * NB_A + 4 * NB_W)) * 256 + threadIdx.x;
    unsigned long long b = __ballot(mask[e] != 0);
    if ((threadIdx.x & 63) == 0) bits[e >> 6] = b;
  }
}

// ---------- GEMM, BK=64, T2-swizzled LDS, double-buffered 1-barrier pipeline ----------
// (R9-verified: BK=64 dbuf beats BK=32 2-barrier by ~10us total — do not revert)
// C[m][n] = alpha * sum_k A[m,k]*B[n,k], K=768
// MODE 0: bf16 row-major (alpha)   MODE 1: khF fragment-major
// MODE 2: vTF fragment-major perm  MODE 3: f32 row-major
template <int MODE, typename CT>
__device__ __forceinline__ void gemm_body(const __bf16* __restrict__ A,
                                          const __bf16* __restrict__ B,
                                          CT* __restrict__ C, int N, int row0,
                                          int col0, float alpha, __bf16* As,
                                          __bf16* Bs) {
  const int K = EMBED;
  const int NIT = K / 64;  // 12
  const int tid = threadIdx.x;
  const int lane = tid & 63;
  const int wave = tid >> 6;
  const int wr = wave >> 1, wc = wave & 1;
  const int l15 = lane & 15, g = lane >> 4;
  f32x4 acc[4][4] = {};

  // staging: LDS row-major [128][64] bf16; gload_lds writes linearly, so the
  // XOR col-swizzle is applied to the GLOBAL source (rule #21) and on reads.
  const int srow = tid >> 3;                 // 0..31
  const int scol8 = (tid & 7) ^ (srow & 7);  // pre-swizzled source col-group
  const __bf16* aS = A + (size_t)(row0 + srow) * K + scol8 * 8;
  const __bf16* bS = B + (size_t)(col0 + srow) * K + scol8 * 8;
  __bf16* aL = As + wave * 512;  // wave covers 8 rows per issue
  __bf16* bL = Bs + wave * 512;

  auto stage = [&](int buf, int k0) {
#pragma unroll
    for (int q = 0; q < 4; ++q) {
      gload_lds16(aS + k0 + (size_t)(q * 32) * K, aL + buf * 8192 + q * 2048);
      gload_lds16(bS + k0 + (size_t)(q * 32) * K, bL + buf * 8192 + q * 2048);
    }
  };

  stage(0, 0);  // prologue
#pragma unroll 2
  for (int it = 0; it < NIT; ++it) {
    const int c = it & 1;
    phase_barrier();  // buf c ready; all prior ds_reads consumed
    if (it + 1 < NIT) stage(1 - c, (it + 1) * 64);  // prefetch overlaps compute
    const __bf16* Asc = As + c * 8192;
    const __bf16* Bsc = Bs + c * 8192;
    bf16x8 af[2][4], bfr[2][4];
#pragma unroll
    for (int i = 0; i < 4; ++i) {
      int row = wr * 64 + i * 16 + l15;
#pragma unroll
      for (int kk = 0; kk < 2; ++kk)
        af[kk][i] =
            *(const bf16x8*)(Asc + row * 64 + ((kk * 4 + g) ^ (row & 7)) * 8);
    }
#pragma unroll
    for (int j = 0; j < 4; ++j) {
      int row = wc * 64 + j * 16 + l15;
#pragma unroll
      for (int kk = 0; kk < 2; ++kk)
        bfr[kk][j] =
            *(const bf16x8*)(Bsc + row * 64 + ((kk * 4 + g) ^ (row & 7)) * 8);
    }
    __builtin_amdgcn_s_setprio(1);
#pragma unroll
    for (int kk = 0; kk < 2; ++kk)
#pragma unroll
      for (int i = 0; i < 4; ++i)
#pragma unroll
        for (int j = 0; j < 4; ++j)
          acc[i][j] = __builtin_amdgcn_mfma_f32_16x16x32_bf16(
              af[kk][i], bfr[kk][j], acc[i][j], 0, 0, 0);
    __builtin_amdgcn_s_setprio(0);
  }
  // C/D layout: col=lane&15, row=(lane>>4)*4+reg  [m89]
#pragma unroll
  for (int i = 0; i < 4; ++i)
#pragma unroll
    for (int j = 0; j < 4; ++j) {
#pragma unroll
      for (int r = 0; r < 4; ++r) {
        float val = alpha * acc[i][j][r];
        int mrow = row0 + wr * 64 + i * 16 + g * 4 + r;   // A-row
        int ncol = col0 + wc * 64 + j * 16 + l15;          // B-row
        if (MODE == 0 || MODE == 3) {
          C[(size_t)mrow * N + ncol] = (CT)val;
        } else if (MODE == 1) {
          // A-rows = tokens, B-rows = features -> khF fragment-major
          int tok = mrow, fcol = ncol;
          int h = fcol >> 6, d = fcol & 63;
          int bh = (tok >> 11) * NHEAD + h;
          int t = (tok >> 6) & 31, kk = tok & 63;
          size_t idx = ((size_t)bh * 32 + t) * 4096 +
                       ((((kk >> 4) * 2 + (d >> 5)) * 64 + ((d >> 3) & 3) * 16 +
                         (kk & 15)) *
                            8 +
                        (d & 7));
          C[idx] = (CT)val;
        } else {
          // MODE 2: A-rows = features, B-rows = tokens -> vTF fragment-major, kv-permuted
          int fr = mrow, tok = ncol;
          int h = fr >> 6, d = fr & 63;
          int dt = d >> 4, l15c = d & 15;
          int bh = (tok >> 11) * NHEAD + h;
          int t = (tok >> 6) & 31, kk = tok & 63;
          int pc = (kk & 32) | ((kk & 12) << 1) | ((kk & 16) >> 2) | (kk & 3);
          int ks = pc >> 5, Gb = (pc >> 3) & 3, e = pc & 7;
          size_t idx = ((size_t)bh * 32 + t) * 4096 +
                       (((ks * 4 + dt) * 64 + Gb * 16 + l15c) * 8 + e);
          C[idx] = (CT)val;
        }
      }
    }
}

__global__ __launch_bounds__(256) void gemm_qkv(
    const __bf16* __restrict__ Qb, const __bf16* __restrict__ Kb,
    const __bf16* __restrict__ Vb, const __bf16* __restrict__ Wqb,
    const __bf16* __restrict__ Wkb, const __bf16* __restrict__ Wvb,
    __bf16* __restrict__ qh, __bf16* __restrict__ khF, __bf16* __restrict__ vTF) {
  __shared__ __align__(16) __bf16 As[2 * 128 * 64];
  __shared__ __align__(16) __bf16 Bs[2 * 128 * 64];
  if (blockIdx.z == 0)
    gemm_body<0, __bf16>(Qb, Wqb, qh, EMBED, blockIdx.x * 128,
                         blockIdx.y * 128, SCALE_LOG2, As, Bs);
  else if (blockIdx.z == 1)
    gemm_body<1, __bf16>(Kb, Wkb, khF, 0, blockIdx.x * 128, blockIdx.y * 128,
                         1.f, As, Bs);
  else
    gemm_body<2, __bf16>(Wvb, Vb, vTF, 0, blockIdx.y * 128, blockIdx.x * 128,
                         1.f, As, Bs);
}

__global__ __launch_bounds__(256) void gemm_out(const __bf16* __restrict__ AO,
                                                const __bf16* __restrict__ Wob,
                                                float* __restrict__ out) {
  __shared__ __align__(16) __bf16 As[2 * 128 * 64];
  __shared__ __align__(16) __bf16 Bs[2 * 128 * 64];
  gemm_body<3, float>(AO, Wob, out, EMBED, blockIdx.x * 128, blockIdx.y * 128,
                      1.f, As, Bs);
}

// ---------- flash attention: R9 config (4-wave, dbuf 1-barrier, KV-split=2) ----------
__global__ __launch_bounds__(256, 4) void flash_attn(
    const __bf16* __restrict__ qh, const __bf16* __restrict__ khF,
    const __bf16* __restrict__ vTF, const unsigned long long* __restrict__ mbits,
    float* __restrict__ Opart, float* __restrict__ lpart) {
  __shared__ __align__(16) __bf16 Ks[2][4096];  // 2 x 8KB frag-major K tile
  __shared__ __align__(16) __bf16 Vs[2][4096];  // 2 x 8KB frag-major V tile
  // XCD-aware bijective swizzle: 768 blocks = 8 XCDs x 96
  int lin = blockIdx.x + 16 * (blockIdx.y + NBH * blockIdx.z);
  int wid = (lin & 7) * 96 + (lin >> 3);
  int qb = wid & 15;
  int rest = wid >> 4;  // 0..47
  int bh = rest % NBH;
  int z = rest / NBH;

  const int tid = threadIdx.x;
  const int lane = tid & 63, w = tid >> 6;
  const int l15 = lane & 15, G = lane >> 4;
  const int b = bh / NHEAD, h = bh % NHEAD;
  const int qrow0 = qb * 128 + w * 32;

  bf16x8 qf[2][2];
#pragma unroll
  for (int qg = 0; qg < 2; ++qg) {
    const __bf16* qptr =
        qh + ((size_t)b * SEQ + qrow0 + qg * 16 + l15) * EMBED + h * HDIM + G * 8;
    qf[qg][0] = *(const bf16x8*)qptr;
    qf[qg][1] = *(const bf16x8*)(qptr + 32);
  }
  const u32x4 onesr = {0x3F803F80u, 0x3F803F80u, 0x3F803F80u, 0x3F803F80u};
  const bf16x8 ones = __builtin_bit_cast(bf16x8, onesr);

  f32x4 o[2][4] = {};  // o[qg][dt][r] = O[q=l15][d = dt*16 + G*4 + r] (unnormalized)
  f32x4 ol[2] = {};    // ol[qg][*] = l[q=l15] via ones-A MFMA

  const __bf16* ktile =
      khF + ((size_t)bh * 32 + z * TILES_PER_SPLIT) * 4096 + tid * 8;
  const __bf16* vtile =
      vTF + ((size_t)bh * 32 + z * TILES_PER_SPLIT) * 4096 + tid * 8;
  const unsigned long long* mrow0 =
      mbits + (size_t)(qrow0 + l15) * 32 + z * TILES_PER_SPLIT;
  const unsigned long long* mrow1 = mrow0 + 16 * 32;

  // prologue: stage tile 0 into buf 0, load its mask words
  gload_lds16(ktile, &Ks[0][0] + w * 512);
  gload_lds16(ktile + 2048, &Ks[0][0] + w * 512 + 2048);
  gload_lds16(vtile, &Vs[0][0] + w * 512);
  gload_lds16(vtile + 2048, &Vs[0][0] + w * 512 + 2048);
  unsigned long long mb0 = mrow0[0], mb1 = mrow1[0];

#pragma unroll 2
  for (int tt = 0; tt < TILES_PER_SPLIT; ++tt) {
    const int c = tt & 1;
    phase_barrier();  // buf c ready; all prior ds_reads consumed
    unsigned long long nmb0 = 0, nmb1 = 0;
    if (tt + 1 < TILES_PER_SPLIT) {  // prefetch tile tt+1 under this compute
      const __bf16* kt = ktile + (size_t)(tt + 1) * 4096;
      const __bf16* vt = vtile + (size_t)(tt + 1) * 4096;
      __bf16* kd = &Ks[1 - c][0] + w * 512;
      __bf16* vd = &Vs[1 - c][0] + w * 512;
      gload_lds16(kt, kd);
      gload_lds16(kt + 2048, kd + 2048);
      gload_lds16(vt, vd);
      gload_lds16(vt + 2048, vd + 2048);
      nmb0 = mrow0[tt + 1];
      nmb1 = mrow1[tt + 1];
    }

    // S^T per q-group: lane holds S[q=l15][kv = jj*16 + G*4 + r]
    f32x4 s[2][4];
    __builtin_amdgcn_s_setprio(1);
#pragma unroll
    for (int jj = 0; jj < 4; ++jj) {
      bf16x8 kf0 = *(const bf16x8*)(&Ks[c][0] + (jj * 2 + 0) * 512 + lane * 8);
      bf16x8 kf1 = *(const bf16x8*)(&Ks[c][0] + (jj * 2 + 1) * 512 + lane * 8);
#pragma unroll
      for (int qg = 0; qg < 2; ++qg) {
        f32x4 zz = {};
        zz = __builtin_amdgcn_mfma_f32_16x16x32_bf16(kf0, qf[qg][0], zz, 0, 0, 0);
        zz = __builtin_amdgcn_mfma_f32_16x16x32_bf16(kf1, qf[qg][1], zz, 0, 0, 0);
        s[qg][jj] = zz;
      }
    }
    __builtin_amdgcn_s_setprio(0);

    // no-max softmax: p = exp2(logit) & signmask(bit)  (masked -> 0.0f)
    unsigned pfw[2][2][4];
#pragma unroll
    for (int qg = 0; qg < 2; ++qg) {
      unsigned long long mb = qg == 0 ? mb0 : mb1;
      unsigned mlo = ((unsigned)mb) >> (G * 4);
      unsigned mhi = ((unsigned)(mb >> 32)) >> (G * 4);
#pragma unroll
      for (int jj = 0; jj < 4; ++jj) {
        unsigned bits = (jj < 2 ? mlo : mhi) >> ((jj & 1) * 16);
#pragma unroll
        for (int r = 0; r < 4; ++r) {
          float p = __builtin_amdgcn_exp2f(s[qg][jj][r]);
          int sm = ((int)(bits << (31 - r))) >> 31;  // 0 or -1
          s[qg][jj][r] = __builtin_bit_cast(
              float, __builtin_bit_cast(unsigned, p) & (unsigned)sm);
        }
      }
      // pack P fragments (order matches vTF's kv permutation)
#pragma unroll
      for (int ks = 0; ks < 2; ++ks) {
        pfw[qg][ks][0] = pack2(s[qg][2 * ks][0], s[qg][2 * ks][1]);
        pfw[qg][ks][1] = pack2(s[qg][2 * ks][2], s[qg][2 * ks][3]);
        pfw[qg][ks][2] = pack2(s[qg][2 * ks + 1][0], s[qg][2 * ks + 1][1]);
        pfw[qg][ks][3] = pack2(s[qg][2 * ks + 1][2], s[qg][2 * ks + 1][3]);
      }
    }
    // PV + l accumulation: V fragments from LDS, shared across both q-groups
    __builtin_amdgcn_s_setprio(1);
#pragma unroll
    for (int ks = 0; ks < 2; ++ks) {
      u32x4 p0 = {pfw[0][ks][0], pfw[0][ks][1], pfw[0][ks][2], pfw[0][ks][3]};
      u32x4 p1 = {pfw[1][ks][0], pfw[1][ks][1], pfw[1][ks][2], pfw[1][ks][3]};
      bf16x8 pf0 = __builtin_bit_cast(bf16x8, p0);
      bf16x8 pf1 = __builtin_bit_cast(bf16x8, p1);
      ol[0] = __builtin_amdgcn_mfma_f32_16x16x32_bf16(ones, pf0, ol[0], 0, 0, 0);
      ol[1] = __builtin_amdgcn_mfma_f32_16x16x32_bf16(ones, pf1, ol[1], 0, 0, 0);
#pragma unroll
      for (int dt = 0; dt < 4; ++dt) {
        bf16x8 vf = *(const bf16x8*)(&Vs[c][0] + (ks * 4 + dt) * 512 + lane * 8);
        o[0][dt] = __builtin_amdgcn_mfma_f32_16x16x32_bf16(vf, pf0, o[0][dt], 0, 0, 0);
        o[1][dt] = __builtin_amdgcn_mfma_f32_16x16x32_bf16(vf, pf1, o[1][dt], 0, 0, 0);
      }
    }
    __builtin_amdgcn_s_setprio(0);
    mb0 = nmb0;
    mb1 = nmb1;
  }
  // write partials
#pragma unroll
  for (int qg = 0; qg < 2; ++qg) {
    int qrow = qrow0 + qg * 16 + l15;
    size_t obase = (((size_t)z * NBH + bh) * SEQ + qrow) * HDIM;
    f32x4* op = (f32x4*)(Opart + obase);
#pragma unroll
    for (int dt = 0; dt < 4; ++dt) op[dt * 4 + G] = o[qg][dt];
    if (G == 0)
      lpart[((size_t)z * NBH + bh) * SEQ + qrow] = ol[qg][0];
  }
}

// ---------- combine the kv-splits -> AO bf16 (plain sums: m == 0 everywhere) ----------
__global__ __launch_bounds__(256) void combine(const float* __restrict__ Opart,
                                               const float* __restrict__ lpart,
                                               __bf16* __restrict__ AO) {
  int idx = blockIdx.x * 256 + threadIdx.x;  // over NBH*SEQ*16
  int bhq = idx >> 4, dq = idx & 15;
  int bh = bhq >> 11, q = bhq & (SEQ - 1);
  const f32x4* Ov = (const f32x4*)Opart;
  float lsum = 0.f;
  float r0 = 0.f, r1 = 0.f, r2 = 0.f, r3 = 0.f;
#pragma unroll
  for (int s = 0; s < NSPLIT; ++s) {
    lsum += lpart[(size_t)s * NBH * SEQ + bhq];
    f32x4 a = Ov[(size_t)s * NBH * SEQ * 16 + (size_t)bhq * 16 + dq];
    r0 += a[0];
    r1 += a[1];
    r2 += a[2];
    r3 += a[3];
  }
  float inv = 1.f / lsum;
  int bb = bh / NHEAD, hh = bh % NHEAD;
  unsigned* dst =
      (unsigned*)(AO + ((size_t)bb * SEQ + q) * EMBED + hh * HDIM + dq * 4);
  dst[0] = pack2(r0 * inv, r1 * inv);
  dst[1] = pack2(r2 * inv, r3 * inv);
}

// ---------- launch ----------
extern "C" void kernel_launch(void* const* d_in, const int* in_sizes, int n_in,
                              void* d_out, int out_size, void* d_ws,
                              size_t ws_size, hipStream_t stream) {
  const float* Q = (const float*)d_in[0];
  const float* K = (const float*)d_in[1];
  const float* V = (const float*)d_in[2];
  const int* mask = (const int*)d_in[3];
  const float* Wq = (const float*)d_in[4];
  const float* Wk = (const float*)d_in[5];
  const float* Wv = (const float*)d_in[6];
  const float* Wo = (const float*)d_in[7];
  float* out = (float*)d_out;

  char* ws = (char*)d_ws;
  const size_t ACT = (size_t)NTOK * EMBED * 2;   // 6.29 MB bf16
  const size_t WMT = (size_t)EMBED * EMBED * 2;  // 1.18 MB bf16
  const size_t OPART_B = (size_t)NSPLIT * NBH * SEQ * HDIM * 4;  // 25.2 MB

  // Opart overlays the dead-after-gemm_qkv region {Qb,Kb,Vb,Wqb,Wkb,Wvb} (22.4 MB)
  float* Opart = (float*)ws;
  __bf16* Qb = (__bf16*)ws;
  __bf16* Kb = (__bf16*)(ws + ACT);
  __bf16* Vb = (__bf16*)(ws + 2 * ACT);
  __bf16* Wqb = (__bf16*)(ws + 3 * ACT);
  __bf16* Wkb = (__bf16*)(ws + 3 * ACT + WMT);
  __bf16* Wvb = (__bf16*)(ws + 3 * ACT + 2 * WMT);
  size_t off = OPART_B;
  auto alloc = [&](size_t bytes) {
    char* p = ws + off;
    off += (bytes + 255) & ~(size_t)255;
    return p;
  };
  __bf16* Wob = (__bf16*)alloc(WMT);
  __bf16* qh = (__bf16*)alloc(ACT);
  __bf16* khF = (__bf16*)alloc(ACT);
  __bf16* vTF = (__bf16*)alloc(ACT);
  __bf16* AO = (__bf16*)alloc(ACT);
  unsigned long long* mbits =
      (unsigned long long*)alloc((size_t)SEQ * (SEQ / 64) * 8);       // 512 KB
  float* lpart = (float*)alloc((size_t)NSPLIT * NBH * SEQ * 4);       // 393 KB

  prep<<<dim3(3 * NB_A + 4 * NB_W + NB_M), 256, 0, stream>>>(
      Q, K, V, Wq, Wk, Wv, Wo, mask, Qb, Kb, Vb, Wqb, Wkb, Wvb, Wob, mbits);
  gemm_qkv<<<dim3(NTOK / 128, EMBED / 128, 3), 256, 0, stream>>>(
      Qb, Kb, Vb, Wqb, Wkb, Wvb, qh, khF, vTF);
  flash_attn<<<dim3(SEQ / 128, NBH, NSPLIT), 256, 0, stream>>>(qh, khF, vTF,
                                                               mbits, Opart,
                                                               lpart);
  combine<<<dim3(NBH * SEQ * 16 / 256), 256, 0, stream>>>(Opart, lpart, AO);
  gemm_out<<<dim3(NTOK / 128, EMBED / 128), 256, 0, stream>>>(AO, Wob, out);
  (void)in_sizes; (void)n_in; (void)out_size; (void)ws_size;
}

// Round 17
// 112.965 us; speedup vs baseline: 1.2425x; 1.0029x over previous
//
#include <hip/hip_runtime.h>
#include <cmath>

typedef __bf16 bf16x8 __attribute__((ext_vector_type(8)));
typedef float f32x4 __attribute__((ext_vector_type(4)));
typedef unsigned int u32x4 __attribute__((ext_vector_type(4)));

#define SEQ 2048
#define EMBED 768
#define NHEAD 12
#define HDIM 64
#define NTOK 4096   // BS*SEQ
#define NBH 24      // BS*NHEAD
#define NSPLIT 2
#define TILES_PER_SPLIT (SEQ / 64 / NSPLIT)  // 16
// base-2 logits: fold log2(e)/sqrt(768) into the q projection
#define SCALE_LOG2 (1.4426950408889634f * 0.036084391824351615f)

// ---------- helpers ----------
__device__ __forceinline__ void gload_lds16(const __bf16* g, __bf16* l) {
  __builtin_amdgcn_global_load_lds(
      (const __attribute__((address_space(1))) void*)g,
      (__attribute__((address_space(3))) void*)l, 16, 0, 0);
}

__device__ __forceinline__ unsigned pack2(float a, float b) {
  unsigned short lo = __builtin_bit_cast(unsigned short, (__bf16)a);
  unsigned short hi = __builtin_bit_cast(unsigned short, (__bf16)b);
  return (unsigned)lo | ((unsigned)hi << 16);
}

// one barrier per pipeline phase: drain my DMA, sync, pin the scheduler
__device__ __forceinline__ void phase_barrier() {
  asm volatile("s_waitcnt vmcnt(0)" ::: "memory");
  __builtin_amdgcn_s_barrier();
  __builtin_amdgcn_sched_barrier(0);
}

// ---------- fused prep: fp32->bf16 converts (G13-vectorized) + mask bitpack ----------
#define NB_A (NTOK * EMBED / 2048)   // 1536 blocks per activation tensor
#define NB_W (EMBED * EMBED / 2048)  // 288 blocks per weight
#define NB_M (SEQ * SEQ / 256)       // 16384 blocks for mask
__global__ __launch_bounds__(256) void prep(
    const float* __restrict__ Q, const float* __restrict__ K,
    const float* __restrict__ V, const float* __restrict__ Wq,
    const float* __restrict__ Wk, const float* __restrict__ Wv,
    const float* __restrict__ Wo, const int* __restrict__ mask,
    __bf16* __restrict__ Qb, __bf16* __restrict__ Kb, __bf16* __restrict__ Vb,
    __bf16* __restrict__ Wqb, __bf16* __restrict__ Wkb,
    __bf16* __restrict__ Wvb, __bf16* __restrict__ Wob,
    unsigned long long* __restrict__ bits) {
  int bid = blockIdx.x;
  if (bid < 3 * NB_A + 4 * NB_W) {
    const float* s;
    __bf16* d;
    int sub;
    if (bid < 3 * NB_A) {
      int which = bid / NB_A;
      sub = bid % NB_A;
      s = which == 0 ? Q : which == 1 ? K : V;
      d = which == 0 ? Qb : which == 1 ? Kb : Vb;
    } else {
      int r = bid - 3 * NB_A;
      int which = r / NB_W;
      sub = r % NB_W;
      s = which == 0 ? Wq : which == 1 ? Wk : which == 2 ? Wv : Wo;
      d = which == 0 ? Wqb : which == 1 ? Wkb : which == 2 ? Wvb : Wob;
    }
    size_t i = ((size_t)sub * 256 + threadIdx.x) * 8;
    float4 a = *(const float4*)(s + i);
    float4 c = *(const float4*)(s + i + 4);
    bf16x8 r;
    r[0] = (__bf16)a.x; r[1] = (__bf16)a.y; r[2] = (__bf16)a.z; r[3] = (__bf16)a.w;
    r[4] = (__bf16)c.x; r[5] = (__bf16)c.y; r[6] = (__bf16)c.z; r[7] = (__bf16)c.w;
    *(bf16x8*)(d + i) = r;
  } else {
    int e = (bid - (3 * NB_A + 4 * NB_W)) * 256 + threadIdx.x;
    unsigned long long b = __ballot(mask[e] != 0);
    if ((threadIdx.x & 63) == 0) bits[e >> 6] = b;
  }
}

// ---------- GEMM, BK=64, T2-swizzled LDS, double-buffered 1-barrier pipeline ----------
// (R9-verified: BK=64 dbuf beats BK=32 2-barrier by ~10us total — do not revert)
// C[m][n] = alpha * sum_k A[m,k]*B[n,k], K=768
// MODE 0: bf16 row-major (alpha)   MODE 1: khF fragment-major
// MODE 2: vTF fragment-major perm  MODE 3: f32 row-major
template <int MODE, typename CT>
__device__ __forceinline__ void gemm_body(const __bf16* __restrict__ A,
                                          const __bf16* __restrict__ B,
                                          CT* __restrict__ C, int N, int row0,
                                          int col0, float alpha, __bf16* As,
                                          __bf16* Bs) {
  const int K = EMBED;
  const int NIT = K / 64;  // 12
  const int tid = threadIdx.x;
  const int lane = tid & 63;
  const int wave = tid >> 6;
  const int wr = wave >> 1, wc = wave & 1;
  const int l15 = lane & 15, g = lane >> 4;
  f32x4 acc[4][4] = {};

  // staging: LDS row-major [128][64] bf16; gload_lds writes linearly, so the
  // XOR col-swizzle is applied to the GLOBAL source (rule #21) and on reads.
  const int srow = tid >> 3;                 // 0..31
  const int scol8 = (tid & 7) ^ (srow & 7);  // pre-swizzled source col-group
  const __bf16* aS = A + (size_t)(row0 + srow) * K + scol8 * 8;
  const __bf16* bS = B + (size_t)(col0 + srow) * K + scol8 * 8;
  __bf16* aL = As + wave * 512;  // wave covers 8 rows per issue
  __bf16* bL = Bs + wave * 512;

  auto stage = [&](int buf, int k0) {
#pragma unroll
    for (int q = 0; q < 4; ++q) {
      gload_lds16(aS + k0 + (size_t)(q * 32) * K, aL + buf * 8192 + q * 2048);
      gload_lds16(bS + k0 + (size_t)(q * 32) * K, bL + buf * 8192 + q * 2048);
    }
  };

  stage(0, 0);  // prologue
#pragma unroll 2
  for (int it = 0; it < NIT; ++it) {
    const int c = it & 1;
    phase_barrier();  // buf c ready; all prior ds_reads consumed
    if (it + 1 < NIT) stage(1 - c, (it + 1) * 64);  // prefetch overlaps compute
    const __bf16* Asc = As + c * 8192;
    const __bf16* Bsc = Bs + c * 8192;
    bf16x8 af[2][4], bfr[2][4];
#pragma unroll
    for (int i = 0; i < 4; ++i) {
      int row = wr * 64 + i * 16 + l15;
#pragma unroll
      for (int kk = 0; kk < 2; ++kk)
        af[kk][i] =
            *(const bf16x8*)(Asc + row * 64 + ((kk * 4 + g) ^ (row & 7)) * 8);
    }
#pragma unroll
    for (int j = 0; j < 4; ++j) {
      int row = wc * 64 + j * 16 + l15;
#pragma unroll
      for (int kk = 0; kk < 2; ++kk)
        bfr[kk][j] =
            *(const bf16x8*)(Bsc + row * 64 + ((kk * 4 + g) ^ (row & 7)) * 8);
    }
    __builtin_amdgcn_s_setprio(1);
#pragma unroll
    for (int kk = 0; kk < 2; ++kk)
#pragma unroll
      for (int i = 0; i < 4; ++i)
#pragma unroll
        for (int j = 0; j < 4; ++j)
          acc[i][j] = __builtin_amdgcn_mfma_f32_16x16x32_bf16(
              af[kk][i], bfr[kk][j], acc[i][j], 0, 0, 0);
    __builtin_amdgcn_s_setprio(0);
  }
  // C/D layout: col=lane&15, row=(lane>>4)*4+reg  [m89]
#pragma unroll
  for (int i = 0; i < 4; ++i)
#pragma unroll
    for (int j = 0; j < 4; ++j) {
#pragma unroll
      for (int r = 0; r < 4; ++r) {
        float val = alpha * acc[i][j][r];
        int mrow = row0 + wr * 64 + i * 16 + g * 4 + r;   // A-row
        int ncol = col0 + wc * 64 + j * 16 + l15;          // B-row
        if (MODE == 0 || MODE == 3) {
          C[(size_t)mrow * N + ncol] = (CT)val;
        } else if (MODE == 1) {
          // A-rows = tokens, B-rows = features -> khF fragment-major
          int tok = mrow, fcol = ncol;
          int h = fcol >> 6, d = fcol & 63;
          int bh = (tok >> 11) * NHEAD + h;
          int t = (tok >> 6) & 31, kk = tok & 63;
          size_t idx = ((size_t)bh * 32 + t) * 4096 +
                       ((((kk >> 4) * 2 + (d >> 5)) * 64 + ((d >> 3) & 3) * 16 +
                         (kk & 15)) *
                            8 +
                        (d & 7));
          C[idx] = (CT)val;
        } else {
          // MODE 2: A-rows = features, B-rows = tokens -> vTF fragment-major, kv-permuted
          int fr = mrow, tok = ncol;
          int h = fr >> 6, d = fr & 63;
          int dt = d >> 4, l15c = d & 15;
          int bh = (tok >> 11) * NHEAD + h;
          int t = (tok >> 6) & 31, kk = tok & 63;
          int pc = (kk & 32) | ((kk & 12) << 1) | ((kk & 16) >> 2) | (kk & 3);
          int ks = pc >> 5, Gb = (pc >> 3) & 3, e = pc & 7;
          size_t idx = ((size_t)bh * 32 + t) * 4096 +
                       (((ks * 4 + dt) * 64 + Gb * 16 + l15c) * 8 + e);
          C[idx] = (CT)val;
        }
      }
    }
}

__global__ __launch_bounds__(256) void gemm_qkv(
    const __bf16* __restrict__ Qb, const __bf16* __restrict__ Kb,
    const __bf16* __restrict__ Vb, const __bf16* __restrict__ Wqb,
    const __bf16* __restrict__ Wkb, const __bf16* __restrict__ Wvb,
    __bf16* __restrict__ qh, __bf16* __restrict__ khF, __bf16* __restrict__ vTF) {
  __shared__ __align__(16) __bf16 As[2 * 128 * 64];
  __shared__ __align__(16) __bf16 Bs[2 * 128 * 64];
  if (blockIdx.z == 0)
    gemm_body<0, __bf16>(Qb, Wqb, qh, EMBED, blockIdx.x * 128,
                         blockIdx.y * 128, SCALE_LOG2, As, Bs);
  else if (blockIdx.z == 1)
    gemm_body<1, __bf16>(Kb, Wkb, khF, 0, blockIdx.x * 128, blockIdx.y * 128,
                         1.f, As, Bs);
  else
    gemm_body<2, __bf16>(Wvb, Vb, vTF, 0, blockIdx.y * 128, blockIdx.x * 128,
                         1.f, As, Bs);
}

__global__ __launch_bounds__(256) void gemm_out(const __bf16* __restrict__ AO,
                                                const __bf16* __restrict__ Wob,
                                                float* __restrict__ out) {
  __shared__ __align__(16) __bf16 As[2 * 128 * 64];
  __shared__ __align__(16) __bf16 Bs[2 * 128 * 64];
  gemm_body<3, float>(AO, Wob, out, EMBED, blockIdx.x * 128, blockIdx.y * 128,
                      1.f, As, Bs);
}

// ---------- flash attention: R9 config (4-wave, dbuf 1-barrier, KV-split=2) ----------
__global__ __launch_bounds__(256, 4) void flash_attn(
    const __bf16* __restrict__ qh, const __bf16* __restrict__ khF,
    const __bf16* __restrict__ vTF, const unsigned long long* __restrict__ mbits,
    float* __restrict__ Opart, float* __restrict__ lpart) {
  __shared__ __align__(16) __bf16 Ks[2][4096];  // 2 x 8KB frag-major K tile
  __shared__ __align__(16) __bf16 Vs[2][4096];  // 2 x 8KB frag-major V tile
  // XCD-aware bijective swizzle: 768 blocks = 8 XCDs x 96
  int lin = blockIdx.x + 16 * (blockIdx.y + NBH * blockIdx.z);
  int wid = (lin & 7) * 96 + (lin >> 3);
  int qb = wid & 15;
  int rest = wid >> 4;  // 0..47
  int bh = rest % NBH;
  int z = rest / NBH;

  const int tid = threadIdx.x;
  const int lane = tid & 63, w = tid >> 6;
  const int l15 = lane & 15, G = lane >> 4;
  const int b = bh / NHEAD, h = bh % NHEAD;
  const int qrow0 = qb * 128 + w * 32;

  bf16x8 qf[2][2];
#pragma unroll
  for (int qg = 0; qg < 2; ++qg) {
    const __bf16* qptr =
        qh + ((size_t)b * SEQ + qrow0 + qg * 16 + l15) * EMBED + h * HDIM + G * 8;
    qf[qg][0] = *(const bf16x8*)qptr;
    qf[qg][1] = *(const bf16x8*)(qptr + 32);
  }
  const u32x4 onesr = {0x3F803F80u, 0x3F803F80u, 0x3F803F80u, 0x3F803F80u};
  const bf16x8 ones = __builtin_bit_cast(bf16x8, onesr);

  f32x4 o[2][4] = {};  // o[qg][dt][r] = O[q=l15][d = dt*16 + G*4 + r] (unnormalized)
  f32x4 ol[2] = {};    // ol[qg][*] = l[q=l15] via ones-A MFMA

  const __bf16* ktile =
      khF + ((size_t)bh * 32 + z * TILES_PER_SPLIT) * 4096 + tid * 8;
  const __bf16* vtile =
      vTF + ((size_t)bh * 32 + z * TILES_PER_SPLIT) * 4096 + tid * 8;
  const unsigned long long* mrow0 =
      mbits + (size_t)(qrow0 + l15) * 32 + z * TILES_PER_SPLIT;
  const unsigned long long* mrow1 = mrow0 + 16 * 32;

  // prologue: stage tile 0 into buf 0, load its mask words
  gload_lds16(ktile, &Ks[0][0] + w * 512);
  gload_lds16(ktile + 2048, &Ks[0][0] + w * 512 + 2048);
  gload_lds16(vtile, &Vs[0][0] + w * 512);
  gload_lds16(vtile + 2048, &Vs[0][0] + w * 512 + 2048);
  unsigned long long mb0 = mrow0[0], mb1 = mrow1[0];

#pragma unroll 2
  for (int tt = 0; tt < TILES_PER_SPLIT; ++tt) {
    const int c = tt & 1;
    phase_barrier();  // buf c ready; all prior ds_reads consumed
    unsigned long long nmb0 = 0, nmb1 = 0;
    if (tt + 1 < TILES_PER_SPLIT) {  // prefetch tile tt+1 under this compute
      const __bf16* kt = ktile + (size_t)(tt + 1) * 4096;
      const __bf16* vt = vtile + (size_t)(tt + 1) * 4096;
      __bf16* kd = &Ks[1 - c][0] + w * 512;
      __bf16* vd = &Vs[1 - c][0] + w * 512;
      gload_lds16(kt, kd);
      gload_lds16(kt + 2048, kd + 2048);
      gload_lds16(vt, vd);
      gload_lds16(vt + 2048, vd + 2048);
      nmb0 = mrow0[tt + 1];
      nmb1 = mrow1[tt + 1];
    }

    // S^T per q-group: lane holds S[q=l15][kv = jj*16 + G*4 + r]
    f32x4 s[2][4];
    __builtin_amdgcn_s_setprio(1);
#pragma unroll
    for (int jj = 0; jj < 4; ++jj) {
      bf16x8 kf0 = *(const bf16x8*)(&Ks[c][0] + (jj * 2 + 0) * 512 + lane * 8);
      bf16x8 kf1 = *(const bf16x8*)(&Ks[c][0] + (jj * 2 + 1) * 512 + lane * 8);
#pragma unroll
      for (int qg = 0; qg < 2; ++qg) {
        f32x4 zz = {};
        zz = __builtin_amdgcn_mfma_f32_16x16x32_bf16(kf0, qf[qg][0], zz, 0, 0, 0);
        zz = __builtin_amdgcn_mfma_f32_16x16x32_bf16(kf1, qf[qg][1], zz, 0, 0, 0);
        s[qg][jj] = zz;
      }
    }
    __builtin_amdgcn_s_setprio(0);

    // no-max softmax: p = exp2(logit) & signmask(bit)  (masked -> 0.0f)
    unsigned pfw[2][2][4];
#pragma unroll
    for (int qg = 0; qg < 2; ++qg) {
      unsigned long long mb = qg == 0 ? mb0 : mb1;
      unsigned mlo = ((unsigned)mb) >> (G * 4);
      unsigned mhi = ((unsigned)(mb >> 32)) >> (G * 4);
#pragma unroll
      for (int jj = 0; jj < 4; ++jj) {
        unsigned bits = (jj < 2 ? mlo : mhi) >> ((jj & 1) * 16);
#pragma unroll
        for (int r = 0; r < 4; ++r) {
          float p = __builtin_amdgcn_exp2f(s[qg][jj][r]);
          int sm = ((int)(bits << (31 - r))) >> 31;  // 0 or -1
          s[qg][jj][r] = __builtin_bit_cast(
              float, __builtin_bit_cast(unsigned, p) & (unsigned)sm);
        }
      }
      // pack P fragments (order matches vTF's kv permutation)
#pragma unroll
      for (int ks = 0; ks < 2; ++ks) {
        pfw[qg][ks][0] = pack2(s[qg][2 * ks][0], s[qg][2 * ks][1]);
        pfw[qg][ks][1] = pack2(s[qg][2 * ks][2], s[qg][2 * ks][3]);
        pfw[qg][ks][2] = pack2(s[qg][2 * ks + 1][0], s[qg][2 * ks + 1][1]);
        pfw[qg][ks][3] = pack2(s[qg][2 * ks + 1][2], s[qg][2 * ks + 1][3]);
      }
    }
    // PV + l accumulation: V fragments from LDS, shared across both q-groups
    __builtin_amdgcn_s_setprio(1);
#pragma unroll
    for (int ks = 0; ks < 2; ++ks) {
      u32x4 p0 = {pfw[0][ks][0], pfw[0][ks][1], pfw[0][ks][2], pfw[0][ks][3]};
      u32x4 p1 = {pfw[1][ks][0], pfw[1][ks][1], pfw[1][ks][2], pfw[1][ks][3]};
      bf16x8 pf0 = __builtin_bit_cast(bf16x8, p0);
      bf16x8 pf1 = __builtin_bit_cast(bf16x8, p1);
      ol[0] = __builtin_amdgcn_mfma_f32_16x16x32_bf16(ones, pf0, ol[0], 0, 0, 0);
      ol[1] = __builtin_amdgcn_mfma_f32_16x16x32_bf16(ones, pf1, ol[1], 0, 0, 0);
#pragma unroll
      for (int dt = 0; dt < 4; ++dt) {
        bf16x8 vf = *(const bf16x8*)(&Vs[c][0] + (ks * 4 + dt) * 512 + lane * 8);
        o[0][dt] = __builtin_amdgcn_mfma_f32_16x16x32_bf16(vf, pf0, o[0][dt], 0, 0, 0);
        o[1][dt] = __builtin_amdgcn_mfma_f32_16x16x32_bf16(vf, pf1, o[1][dt], 0, 0, 0);
      }
    }
    __builtin_amdgcn_s_setprio(0);
    mb0 = nmb0;
    mb1 = nmb1;
  }
  // write partials
#pragma unroll
  for (int qg = 0; qg < 2; ++qg) {
    int qrow = qrow0 + qg * 16 + l15;
    size_t obase = (((size_t)z * NBH + bh) * SEQ + qrow) * HDIM;
    f32x4* op = (f32x4*)(Opart + obase);
#pragma unroll
    for (int dt = 0; dt < 4; ++dt) op[dt * 4 + G] = o[qg][dt];
    if (G == 0)
      lpart[((size_t)z * NBH + bh) * SEQ + qrow] = ol[qg][0];
  }
}

// ---------- combine the kv-splits -> AO bf16 (plain sums: m == 0 everywhere) ----------
__global__ __launch_bounds__(256) void combine(const float* __restrict__ Opart,
                                               const float* __restrict__ lpart,
                                               __bf16* __restrict__ AO) {
  int idx = blockIdx.x * 256 + threadIdx.x;  // over NBH*SEQ*16
  int bhq = idx >> 4, dq = idx & 15;
  int bh = bhq >> 11, q = bhq & (SEQ - 1);
  const f32x4* Ov = (const f32x4*)Opart;
  float lsum = 0.f;
  float r0 = 0.f, r1 = 0.f, r2 = 0.f, r3 = 0.f;
#pragma unroll
  for (int s = 0; s < NSPLIT; ++s) {
    lsum += lpart[(size_t)s * NBH * SEQ + bhq];
    f32x4 a = Ov[(size_t)s * NBH * SEQ * 16 + (size_t)bhq * 16 + dq];
    r0 += a[0];
    r1 += a[1];
    r2 += a[2];
    r3 += a[3];
  }
  float inv = 1.f / lsum;
  int bb = bh / NHEAD, hh = bh % NHEAD;
  unsigned* dst =
      (unsigned*)(AO + ((size_t)bb * SEQ + q) * EMBED + hh * HDIM + dq * 4);
  dst[0] = pack2(r0 * inv, r1 * inv);
  dst[1] = pack2(r2 * inv, r3 * inv);
}

// ---------- launch ----------
extern "C" void kernel_launch(void* const* d_in, const int* in_sizes, int n_in,
                              void* d_out, int out_size, void* d_ws,
                              size_t ws_size, hipStream_t stream) {
  const float* Q = (const float*)d_in[0];
  const float* K = (const float*)d_in[1];
  const float* V = (const float*)d_in[2];
  const int* mask = (const int*)d_in[3];
  const float* Wq = (const float*)d_in[4];
  const float* Wk = (const float*)d_in[5];
  const float* Wv = (const float*)d_in[6];
  const float* Wo = (const float*)d_in[7];
  float* out = (float*)d_out;

  char* ws = (char*)d_ws;
  const size_t ACT = (size_t)NTOK * EMBED * 2;   // 6.29 MB bf16
  const size_t WMT = (size_t)EMBED * EMBED * 2;  // 1.18 MB bf16
  const size_t OPART_B = (size_t)NSPLIT * NBH * SEQ * HDIM * 4;  // 25.2 MB

  // Opart overlays the dead-after-gemm_qkv region {Qb,Kb,Vb,Wqb,Wkb,Wvb} (22.4 MB)
  float* Opart = (float*)ws;
  __bf16* Qb = (__bf16*)ws;
  __bf16* Kb = (__bf16*)(ws + ACT);
  __bf16* Vb = (__bf16*)(ws + 2 * ACT);
  __bf16* Wqb = (__bf16*)(ws + 3 * ACT);
  __bf16* Wkb = (__bf16*)(ws + 3 * ACT + WMT);
  __bf16* Wvb = (__bf16*)(ws + 3 * ACT + 2 * WMT);
  size_t off = OPART_B;
  auto alloc = [&](size_t bytes) {
    char* p = ws + off;
    off += (bytes + 255) & ~(size_t)255;
    return p;
  };
  __bf16* Wob = (__bf16*)alloc(WMT);
  __bf16* qh = (__bf16*)alloc(ACT);
  __bf16* khF = (__bf16*)alloc(ACT);
  __bf16* vTF = (__bf16*)alloc(ACT);
  __bf16* AO = (__bf16*)alloc(ACT);
  unsigned long long* mbits =
      (unsigned long long*)alloc((size_t)SEQ * (SEQ / 64) * 8);       // 512 KB
  float* lpart = (float*)alloc((size_t)NSPLIT * NBH * SEQ * 4);       // 393 KB

  prep<<<dim3(3 * NB_A + 4 * NB_W + NB_M), 256, 0, stream>>>(
      Q, K, V, Wq, Wk, Wv, Wo, mask, Qb, Kb, Vb, Wqb, Wkb, Wvb, Wob, mbits);
  gemm_qkv<<<dim3(NTOK / 128, EMBED / 128, 3), 256, 0, stream>>>(
      Qb, Kb, Vb, Wqb, Wkb, Wvb, qh, khF, vTF);
  flash_attn<<<dim3(SEQ / 128, NBH, NSPLIT), 256, 0, stream>>>(qh, khF, vTF,
                                                               mbits, Opart,
                                                               lpart);
  combine<<<dim3(NBH * SEQ * 16 / 256), 256, 0, stream>>>(Opart, lpart, AO);
  gemm_out<<<dim3(NTOK / 128, EMBED / 128), 256, 0, stream>>>(AO, Wob, out);
  (void)in_sizes; (void)n_in; (void)out_size; (void)ws_size;
}